// Round 10
// baseline (277.488 us; speedup 1.0000x reference)
//
#include <hip/hip_runtime.h>
#include <hip/hip_fp16.h>

#define CIN 128
#define CH 256
#define COUT 128
#define BN_EPS 1e-5f

typedef __attribute__((ext_vector_type(8))) short bf16x8;
typedef __attribute__((ext_vector_type(4))) float f32x4;

// float -> bf16 (round-to-nearest-even), raw short
__device__ __forceinline__ short f2bf(float x) {
    unsigned u = __float_as_uint(x);
    unsigned r = (u + 0x7fffu + ((u >> 16) & 1u)) >> 16;
    return (short)r;
}
__device__ __forceinline__ float bf2f(short h) {
    return __uint_as_float(((unsigned)(unsigned short)h) << 16);
}

// count in-degree; record each edge's rank within its dst bucket
__global__ void k_deg(const int* __restrict__ dst, int* __restrict__ degi,
                      unsigned short* __restrict__ rank, int E) {
    int e = blockIdx.x * 256 + threadIdx.x;
    if (e < E) rank[e] = (unsigned short)atomicAdd(&degi[dst[e]], 1);
}

// block sums of degi + fused dinv = rsqrt(deg+1)
__global__ void k_scan1(const int* __restrict__ degi, float* __restrict__ dinv,
                        int* __restrict__ blocksum, int N) {
    __shared__ int s[256];
    int i = blockIdx.x * 256 + threadIdx.x;
    int v = (i < N) ? degi[i] : 0;
    if (i < N) dinv[i] = rsqrtf((float)(v + 1));
    s[threadIdx.x] = v;
    __syncthreads();
    for (int st = 128; st > 0; st >>= 1) {
        if (threadIdx.x < st) s[threadIdx.x] += s[threadIdx.x + st];
        __syncthreads();
    }
    if (threadIdx.x == 0) blocksum[blockIdx.x] = s[0];
}

// per-element exclusive scan; every block redundantly scans blocksum in LDS. nb <= 256.
__global__ void k_scan3(const int* __restrict__ degi, const int* __restrict__ blocksum,
                        int nb, int* __restrict__ rowstart, int N, int E) {
    __shared__ int sb[256];
    __shared__ int s[256];
    int bv = (threadIdx.x < nb) ? blocksum[threadIdx.x] : 0;
    sb[threadIdx.x] = bv;
    __syncthreads();
    for (int st = 1; st < 256; st <<= 1) {
        int t = (threadIdx.x >= st) ? sb[threadIdx.x - st] : 0;
        __syncthreads();
        sb[threadIdx.x] += t;
        __syncthreads();
    }
    int boff = (blockIdx.x == 0) ? 0 : sb[blockIdx.x - 1];

    int i = blockIdx.x * 256 + threadIdx.x;
    int v = (i < N) ? degi[i] : 0;
    s[threadIdx.x] = v;
    __syncthreads();
    for (int st = 1; st < 256; st <<= 1) {
        int t = (threadIdx.x >= st) ? s[threadIdx.x - st] : 0;
        __syncthreads();
        s[threadIdx.x] += t;
        __syncthreads();
    }
    if (i < N) rowstart[i] = s[threadIdx.x] - v + boff;
    if (blockIdx.x == 0 && threadIdx.x == 0) rowstart[N] = E;
}

// atomic-free scatter: pos = rowstart[dst] + rank; 2-byte src record
__global__ void k_fill(const int* __restrict__ src, const int* __restrict__ dst,
                       const unsigned short* __restrict__ rank,
                       const int* __restrict__ rowstart,
                       unsigned short* __restrict__ csr, int E) {
    int e = blockIdx.x * 256 + threadIdx.x;
    if (e >= E) return;
    int d = dst[e];
    int pos = rowstart[d] + (int)rank[e];
    __builtin_nontemporal_store((unsigned short)src[e], &csr[pos]);
}

// fused prep:
//  - W1,W2 -> bf16 split (hi+lo), pre-swizzled into MFMA B-fragment order:
//    per (col16-tile, ks): 1KB block, lane L holds its bf16x8; hi at +0, lo at +512 shorts.
//  - node features -> bf16
__global__ void k_prep(const float* __restrict__ W1, const float* __restrict__ W2,
                       short* __restrict__ W1sw, short* __restrict__ W2sw,
                       const float4* __restrict__ nf, short4* __restrict__ nfb, int n4) {
    int t = blockIdx.x * 256 + threadIdx.x;
    if (t < 32768) {                 // W1 [128][256]: n=col (0..255), kk=k (0..127), KS=4
        int n = t >> 7, kk = t & 127;
        float v = W1[kk * 256 + n];
        short h = f2bf(v);
        short l = f2bf(v - bf2f(h));
        int t16 = n >> 4, m = n & 15;
        int ks = kk >> 5, q = (kk >> 3) & 3, j = kk & 7;
        int idx = (t16 * 4 + ks) * 1024 + (q * 16 + m) * 8 + j;
        W1sw[idx] = h;
        W1sw[idx + 512] = l;
    } else if (t < 65536) {          // W2 [256][128]: n=col (0..127), kk=k (0..255), KS=8
        int u = t - 32768;
        int n = u >> 8, kk = u & 255;
        float v = W2[kk * 128 + n];
        short h = f2bf(v);
        short l = f2bf(v - bf2f(h));
        int t16 = n >> 4, m = n & 15;
        int ks = kk >> 5, q = (kk >> 3) & 3, j = kk & 7;
        int idx = (t16 * 8 + ks) * 1024 + (q * 16 + m) * 8 + j;
        W2sw[idx] = h;
        W2sw[idx + 512] = l;
    } else {
        int u = t - 65536;
        if (u < n4) {
            float4 v = nf[u];
            short4 s;
            s.x = f2bf(v.x); s.y = f2bf(v.y); s.z = f2bf(v.z); s.w = f2bf(v.w);
            nfb[u] = s;
        }
    }
}

// gather over CSR, bf16 input rows [N,128], fp32 accumulate.
// 16 lanes per row, 8 channels (16B) per lane; 8/4/1 edge unroll.
// Edge weight recomputed as dinv[src]*dinv[r] (fp32).
// MODE 0: write bf16 row; MODE 1: write fp32 + bias (final output)
template <int MODE>
__global__ __launch_bounds__(256) void k_gather(const short* __restrict__ xb,
                                                const int* __restrict__ rowstart,
                                                const unsigned short* __restrict__ csr,
                                                const float* __restrict__ dinv,
                                                const float* __restrict__ bias,
                                                float* __restrict__ out,
                                                short* __restrict__ ob, int N) {
    int t = blockIdx.x * 256 + threadIdx.x;
    int r = t >> 4;
    int c = t & 15;              // channels c*8 .. c*8+7
    if (r >= N) return;
    float di = dinv[r];
    float w0 = di * di;
    bf16x8 sv = *(const bf16x8*)(xb + (size_t)r * 128 + c * 8);
    float acc[8];
    #pragma unroll
    for (int j = 0; j < 8; ++j) acc[j] = bf2f(sv[j]) * w0;
    int e0 = rowstart[r], e1 = rowstart[r + 1];
    int e = e0;
    for (; e + 7 < e1; e += 8) {
        int s[8];
        #pragma unroll
        for (int i = 0; i < 8; ++i) s[i] = csr[e + i];
        float w[8];
        #pragma unroll
        for (int i = 0; i < 8; ++i) w[i] = dinv[s[i]] * di;
        bf16x8 x[8];
        #pragma unroll
        for (int i = 0; i < 8; ++i) x[i] = *(const bf16x8*)(xb + (size_t)s[i] * 128 + c * 8);
        #pragma unroll
        for (int i = 0; i < 8; ++i)
            #pragma unroll
            for (int j = 0; j < 8; ++j) acc[j] = fmaf(w[i], bf2f(x[i][j]), acc[j]);
    }
    for (; e + 3 < e1; e += 4) {
        int s[4];
        #pragma unroll
        for (int i = 0; i < 4; ++i) s[i] = csr[e + i];
        float w[4];
        #pragma unroll
        for (int i = 0; i < 4; ++i) w[i] = dinv[s[i]] * di;
        bf16x8 x[4];
        #pragma unroll
        for (int i = 0; i < 4; ++i) x[i] = *(const bf16x8*)(xb + (size_t)s[i] * 128 + c * 8);
        #pragma unroll
        for (int i = 0; i < 4; ++i)
            #pragma unroll
            for (int j = 0; j < 8; ++j) acc[j] = fmaf(w[i], bf2f(x[i][j]), acc[j]);
    }
    for (; e < e1; ++e) {
        int s0 = csr[e];
        float ww = dinv[s0] * di;
        bf16x8 x0 = *(const bf16x8*)(xb + (size_t)s0 * 128 + c * 8);
        #pragma unroll
        for (int j = 0; j < 8; ++j) acc[j] = fmaf(ww, bf2f(x0[j]), acc[j]);
    }
    if (MODE == 0) {
        bf16x8 h;
        #pragma unroll
        for (int j = 0; j < 8; ++j) h[j] = f2bf(acc[j]);
        *(bf16x8*)(ob + (size_t)r * 128 + c * 8) = h;
    } else {
        float4 b0 = *(const float4*)(bias + c * 8);
        float4 b1 = *(const float4*)(bias + c * 8 + 4);
        float4 o0 = make_float4(acc[0] + b0.x, acc[1] + b0.y, acc[2] + b0.z, acc[3] + b0.w);
        float4 o1 = make_float4(acc[4] + b1.x, acc[5] + b1.y, acc[6] + b1.z, acc[7] + b1.w);
        *(float4*)(out + (size_t)r * 128 + c * 8) = o0;
        *(float4*)(out + (size_t)r * 128 + c * 8 + 4) = o1;
    }
}

__device__ __forceinline__ bf16x8 bnrelu8(bf16x8 raw, const float* __restrict__ scsh, int c) {
    float4 sc0 = *(const float4*)(scsh + c);
    float4 sc1 = *(const float4*)(scsh + c + 4);
    float4 sh0 = *(const float4*)(scsh + 256 + c);
    float4 sh1 = *(const float4*)(scsh + 256 + c + 4);
    bf16x8 o;
    o[0] = f2bf(fmaxf(fmaf(bf2f(raw[0]), sc0.x, sh0.x), 0.f));
    o[1] = f2bf(fmaxf(fmaf(bf2f(raw[1]), sc0.y, sh0.y), 0.f));
    o[2] = f2bf(fmaxf(fmaf(bf2f(raw[2]), sc0.z, sh0.z), 0.f));
    o[3] = f2bf(fmaxf(fmaf(bf2f(raw[3]), sc0.w, sh0.w), 0.f));
    o[4] = f2bf(fmaxf(fmaf(bf2f(raw[4]), sc1.x, sh1.x), 0.f));
    o[5] = f2bf(fmaxf(fmaf(bf2f(raw[5]), sc1.y, sh1.y), 0.f));
    o[6] = f2bf(fmaxf(fmaf(bf2f(raw[6]), sc1.z, sh1.z), 0.f));
    o[7] = f2bf(fmaxf(fmaf(bf2f(raw[7]), sc1.w, sh1.w), 0.f));
    return o;
}

// C[M,NOUT](bf16) = f(A)[M,K](bf16) @ W^T (split-bf16, fragment-swizzled) + bias
// f = identity or BN+ReLU (applied during LDS staging). STATS: per-block partial
// sums written to `partials` (no atomics — reduced by k_redstats).
// Block: 256 thr = 4 waves, 64 rows x full NOUT; wave covers NOUT/4 cols (CT tiles).
// A-tile staged in LDS; B via manual 2-stage register double-buffer (loads of
// ks+1 issue under MFMAs of ks). Epilogue staged via LDS for coalesced writes.
template <int K, int NOUT, bool STATS, bool BIAS, bool BNRELU>
__global__ __launch_bounds__(256, 2) void k_gemm(const short* __restrict__ A,
                                                 const short* __restrict__ Bsw,
                                                 const float* __restrict__ bias,
                                                 const float* __restrict__ scsh,
                                                 short* __restrict__ C,
                                                 float* __restrict__ partials, int M) {
    constexpr int CT = NOUT / 64;   // col16-tiles per wave
    constexpr int KS = K / 32;      // k-steps
    constexpr int KP = K + 8;       // padded A row (shorts)
    constexpr int LROW = NOUT + 8;  // padded epilogue row (shorts)
    constexpr int LSZ = (64 * KP > 64 * LROW) ? 64 * KP : 64 * LROW;
    __shared__ __align__(16) short lds[LSZ];
    int tid = threadIdx.x;
    int wave = tid >> 6;
    int lane = tid & 63;
    int m = lane & 15;
    int q = lane >> 4;
    int row0 = blockIdx.x * 64;

    // stage A-tile (64 x K) -> LDS, BN+ReLU fused here when enabled
    constexpr int CPRA = K / 8;     // 16B chunks per A row
    #pragma unroll
    for (int i = 0; i < (64 * CPRA) / 256; ++i) {
        int idx = i * 256 + tid;
        int r = idx / CPRA, cc = idx % CPRA;
        int gr = row0 + r;
        if (gr >= M) gr = M - 1;
        bf16x8 v = *(const bf16x8*)(A + (size_t)gr * K + cc * 8);
        if (BNRELU) v = bnrelu8(v, scsh, cc * 8);
        *(bf16x8*)(lds + r * KP + cc * 8) = v;
    }
    __syncthreads();

    f32x4 acc[4][CT];
    #pragma unroll
    for (int rt = 0; rt < 4; ++rt)
        #pragma unroll
        for (int ct = 0; ct < CT; ++ct)
            acc[rt][ct] = (f32x4){0.f, 0.f, 0.f, 0.f};

    // B double-buffer: prologue loads ks=0
    bf16x8 bh[2][CT], bl[2][CT];
    #pragma unroll
    for (int ct = 0; ct < CT; ++ct) {
        const short* bp = Bsw + (size_t)((wave * CT + ct) * KS) * 1024 + lane * 8;
        bh[0][ct] = *(const bf16x8*)bp;
        bl[0][ct] = *(const bf16x8*)(bp + 512);
    }

    #pragma unroll
    for (int ks = 0; ks < KS; ++ks) {
        const int cur = ks & 1, nxt = cur ^ 1;
        if (ks + 1 < KS) {
            #pragma unroll
            for (int ct = 0; ct < CT; ++ct) {
                const short* bp = Bsw + (size_t)((wave * CT + ct) * KS + ks + 1) * 1024 + lane * 8;
                bh[nxt][ct] = *(const bf16x8*)bp;
                bl[nxt][ct] = *(const bf16x8*)(bp + 512);
            }
        }
        bf16x8 af[4];
        #pragma unroll
        for (int rt = 0; rt < 4; ++rt)
            af[rt] = *(const bf16x8*)(lds + (rt * 16 + m) * KP + ks * 32 + q * 8);
        #pragma unroll
        for (int ct = 0; ct < CT; ++ct)
            #pragma unroll
            for (int rt = 0; rt < 4; ++rt) {
                acc[rt][ct] = __builtin_amdgcn_mfma_f32_16x16x32_bf16(af[rt], bh[cur][ct], acc[rt][ct], 0, 0, 0);
                acc[rt][ct] = __builtin_amdgcn_mfma_f32_16x16x32_bf16(af[rt], bl[cur][ct], acc[rt][ct], 0, 0, 0);
            }
    }
    __syncthreads();   // A-tile reads done; reuse LDS for epilogue

    // epilogue: bias (+stats partials), bf16 -> LDS, then coalesced global writes
    #pragma unroll
    for (int ct = 0; ct < CT; ++ct) {
        int col = wave * (NOUT / 4) + ct * 16 + m;
        float bv = BIAS ? bias[col] : 0.f;
        float s = 0.f, sq = 0.f;
        #pragma unroll
        for (int rt = 0; rt < 4; ++rt) {
            #pragma unroll
            for (int r = 0; r < 4; ++r) {
                int lrow = rt * 16 + q * 4 + r;
                float v = acc[rt][ct][r] + bv;
                if (STATS && row0 + lrow < M) { s += v; sq = fmaf(v, v, sq); }
                lds[lrow * LROW + col] = f2bf(v);
            }
        }
        if (STATS) {
            s += __shfl_xor(s, 16, 64);
            s += __shfl_xor(s, 32, 64);
            sq += __shfl_xor(sq, 16, 64);
            sq += __shfl_xor(sq, 32, 64);
            if (lane < 16) {
                partials[(size_t)blockIdx.x * 512 + col] = s;
                partials[(size_t)blockIdx.x * 512 + 256 + col] = sq;
            }
        }
    }
    __syncthreads();
    constexpr int CPR = NOUT / 8;       // 16B chunks per row
    #pragma unroll
    for (int i = 0; i < (64 * CPR) / 256; ++i) {
        int idx = i * 256 + tid;
        int row = idx / CPR;
        int ch = idx % CPR;
        if (row0 + row < M)
            *(bf16x8*)(C + (size_t)(row0 + row) * NOUT + ch * 8) =
                *(const bf16x8*)(lds + row * LROW + ch * 8);
    }
}

// reduce per-block stat partials [nb][512] -> stats[512]; few atomics per addr
__global__ void k_redstats(const float* __restrict__ partials, float* __restrict__ stats,
                           int nb, int rpb) {
    int sid = threadIdx.x;            // 512 threads: stat index
    int r0 = blockIdx.x * rpb;
    int r1 = r0 + rpb;
    if (r1 > nb) r1 = nb;
    float acc = 0.f;
    for (int r = r0; r < r1; ++r) acc += partials[(size_t)r * 512 + sid];
    unsafeAtomicAdd(&stats[sid], acc);
}

__global__ void k_bnfinal(const float* __restrict__ stats, const float* __restrict__ gamma,
                          const float* __restrict__ beta, float* __restrict__ scsh, int N) {
    int c = threadIdx.x;
    float invN = 1.0f / (float)N;
    float mean = stats[c] * invN;
    float var = stats[256 + c] * invN - mean * mean;
    var = fmaxf(var, 0.f);
    float inv = rsqrtf(var + BN_EPS);
    float sc = gamma[c] * inv;
    scsh[c] = sc;
    scsh[256 + c] = fmaf(-mean, sc, beta[c]);
}

extern "C" void kernel_launch(void* const* d_in, const int* in_sizes, int n_in,
                              void* d_out, int out_size, void* d_ws, size_t ws_size,
                              hipStream_t stream) {
    const float* nf    = (const float*)d_in[0];
    const int*   ei    = (const int*)d_in[1];
    const float* W1    = (const float*)d_in[2];
    const float* b1    = (const float*)d_in[3];
    const float* gamma = (const float*)d_in[4];
    const float* beta  = (const float*)d_in[5];
    const float* W2    = (const float*)d_in[6];
    const float* b2    = (const float*)d_in[7];
    float* out = (float*)d_out;

    const int N = in_sizes[0] / CIN;      // 50000
    const int E = in_sizes[1] / 2;        // 800000
    const int* src = ei;
    const int* dst = ei + E;

    const int nb1 = (N + 63) / 64;        // gemm row-blocks (782)

    char* ws = (char*)d_ws;
    auto align256 = [](size_t x) { return (x + 255) & ~(size_t)255; };
    size_t off = 0;
    int*   degi = (int*)(ws + off);      off += align256((size_t)N * 4);
    float* stats = (float*)(ws + off);   off += align256(512 * 4);
    size_t zspan = off;                  // memset degi+stats in one shot
    float* dinv = (float*)(ws + off);    off += align256((size_t)N * 4);
    int*   rowstart = (int*)(ws + off);  off += align256((size_t)(N + 1) * 4);
    int*   blocksum = (int*)(ws + off);  off += align256(256 * 4);
    float* scsh = (float*)(ws + off);    off += align256(512 * 4);
    short* W1sw = (short*)(ws + off);    off += align256(65536 * 2);   // swizzled hi+lo
    short* W2sw = (short*)(ws + off);    off += align256(65536 * 2);
    float* partials = (float*)(ws + off); off += align256((size_t)nb1 * 512 * 4);
    unsigned short* rank = (unsigned short*)(ws + off); off += align256((size_t)E * 2);
    unsigned short* csr = (unsigned short*)(ws + off);  off += align256((size_t)E * 2);
    short* nfb = (short*)(ws + off);     off += align256((size_t)N * CIN * 2);   // nf bf16
    short* agg1b = (short*)(ws + off);   off += align256((size_t)N * CIN * 2);   // S@x bf16
    short* x1b = (short*)(ws + off);     off += align256((size_t)N * CH * 2);    // layer1 bf16
    short* yb = (short*)(ws + off);      off += align256((size_t)N * COUT * 2);  // bnrelu(x1)@W2 bf16

    int nbN = (N + 255) / 256;
    int nbE = (E + 255) / 256;
    int n4 = N * 32;

    // zero degi + stats in one memset
    hipMemsetAsync(ws, 0, zspan, stream);

    // weight prep (swizzle+split) + feature cast (independent of graph build)
    k_prep<<<(65536 + n4 + 255) / 256, 256, 0, stream>>>(
        W1, W2, W1sw, W2sw, (const float4*)nf, (short4*)nfb, n4);

    // degree (+ per-edge rank) + norm + CSR build (atomic-free fill)
    k_deg<<<nbE, 256, 0, stream>>>(dst, degi, rank, E);
    k_scan1<<<nbN, 256, 0, stream>>>(degi, dinv, blocksum, N);
    k_scan3<<<nbN, 256, 0, stream>>>(degi, blocksum, nbN, rowstart, N, E);
    k_fill<<<nbE, 256, 0, stream>>>(src, dst, rank, rowstart, csr, E);

    // layer 1 aggregation (gather, bf16 in/out)
    k_gather<0><<<(N * 16 + 255) / 256, 256, 0, stream>>>(
        nfb, rowstart, csr, dinv, nullptr, nullptr, agg1b, N);

    // x1 = agg1 @ W1 + b1, per-block BN-stat partials (no atomics)
    k_gemm<CIN, CH, true, true, false><<<nb1, 256, 0, stream>>>(
        agg1b, W1sw, b1, nullptr, x1b, partials, N);

    // reduce partials -> stats, then BN scale/shift
    {
        int rblocks = 8;
        int rpb = (nb1 + rblocks - 1) / rblocks;
        k_redstats<<<rblocks, 512, 0, stream>>>(partials, stats, nb1, rpb);
    }
    k_bnfinal<<<1, 256, 0, stream>>>(stats, gamma, beta, scsh, N);

    // y = relu(bn(x1)) @ W2  (BN+ReLU fused into A staging; bias deferred to gather)
    k_gemm<CH, COUT, false, false, true><<<nb1, 256, 0, stream>>>(
        x1b, W2sw, nullptr, scsh, yb, nullptr, N);

    // out = S @ y + b2
    k_gather<1><<<(N * 16 + 255) / 256, 256, 0, stream>>>(
        yb, rowstart, csr, dinv, b2, out, nullptr, N);
}

// Round 11
// 267.261 us; speedup vs baseline: 1.0383x; 1.0383x over previous
//
#include <hip/hip_runtime.h>
#include <hip/hip_fp16.h>

#define CIN 128
#define CH 256
#define COUT 128
#define BN_EPS 1e-5f

typedef __attribute__((ext_vector_type(8))) short bf16x8;
typedef __attribute__((ext_vector_type(4))) float f32x4;

// float -> bf16 (round-to-nearest-even), raw short
__device__ __forceinline__ short f2bf(float x) {
    unsigned u = __float_as_uint(x);
    unsigned r = (u + 0x7fffu + ((u >> 16) & 1u)) >> 16;
    return (short)r;
}
__device__ __forceinline__ float bf2f(short h) {
    return __uint_as_float(((unsigned)(unsigned short)h) << 16);
}

// count in-degree; record each edge's rank within its dst bucket
__global__ void k_deg(const int* __restrict__ dst, int* __restrict__ degi,
                      unsigned short* __restrict__ rank, int E) {
    int e = blockIdx.x * 256 + threadIdx.x;
    if (e < E) rank[e] = (unsigned short)atomicAdd(&degi[dst[e]], 1);
}

// block sums of degi + fused dinv = rsqrt(deg+1)
__global__ void k_scan1(const int* __restrict__ degi, float* __restrict__ dinv,
                        int* __restrict__ blocksum, int N) {
    __shared__ int s[256];
    int i = blockIdx.x * 256 + threadIdx.x;
    int v = (i < N) ? degi[i] : 0;
    if (i < N) dinv[i] = rsqrtf((float)(v + 1));
    s[threadIdx.x] = v;
    __syncthreads();
    for (int st = 128; st > 0; st >>= 1) {
        if (threadIdx.x < st) s[threadIdx.x] += s[threadIdx.x + st];
        __syncthreads();
    }
    if (threadIdx.x == 0) blocksum[blockIdx.x] = s[0];
}

// per-element exclusive scan; every block redundantly scans blocksum in LDS. nb <= 256.
__global__ void k_scan3(const int* __restrict__ degi, const int* __restrict__ blocksum,
                        int nb, int* __restrict__ rowstart, int N, int E) {
    __shared__ int sb[256];
    __shared__ int s[256];
    int bv = (threadIdx.x < nb) ? blocksum[threadIdx.x] : 0;
    sb[threadIdx.x] = bv;
    __syncthreads();
    for (int st = 1; st < 256; st <<= 1) {
        int t = (threadIdx.x >= st) ? sb[threadIdx.x - st] : 0;
        __syncthreads();
        sb[threadIdx.x] += t;
        __syncthreads();
    }
    int boff = (blockIdx.x == 0) ? 0 : sb[blockIdx.x - 1];

    int i = blockIdx.x * 256 + threadIdx.x;
    int v = (i < N) ? degi[i] : 0;
    s[threadIdx.x] = v;
    __syncthreads();
    for (int st = 1; st < 256; st <<= 1) {
        int t = (threadIdx.x >= st) ? s[threadIdx.x - st] : 0;
        __syncthreads();
        s[threadIdx.x] += t;
        __syncthreads();
    }
    if (i < N) rowstart[i] = s[threadIdx.x] - v + boff;
    if (blockIdx.x == 0 && threadIdx.x == 0) rowstart[N] = E;
}

// atomic-free scatter: pos = rowstart[dst] + rank; 2-byte src record
__global__ void k_fill(const int* __restrict__ src, const int* __restrict__ dst,
                       const unsigned short* __restrict__ rank,
                       const int* __restrict__ rowstart,
                       unsigned short* __restrict__ csr, int E) {
    int e = blockIdx.x * 256 + threadIdx.x;
    if (e >= E) return;
    int d = dst[e];
    int pos = rowstart[d] + (int)rank[e];
    __builtin_nontemporal_store((unsigned short)src[e], &csr[pos]);
}

// fused prep:
//  - W1,W2 -> bf16 (single, no split), pre-swizzled into MFMA B-fragment order:
//    per (col16-tile, ks): 512-short block, lane L holds its bf16x8 at L*8.
//  - node features -> bf16
//  - zero degi and stats (replaces memset dispatch)
__global__ void k_prep(const float* __restrict__ W1, const float* __restrict__ W2,
                       short* __restrict__ W1sw, short* __restrict__ W2sw,
                       const float4* __restrict__ nf, short4* __restrict__ nfb,
                       int* __restrict__ degi, float* __restrict__ stats,
                       int n4, int N) {
    int t = blockIdx.x * 256 + threadIdx.x;
    if (t < 32768) {                 // W1 [128][256]: n=col (0..255), kk=k (0..127), KS=4
        if (t < 512) stats[t] = 0.0f;
        int n = t >> 7, kk = t & 127;
        float v = W1[kk * 256 + n];
        int t16 = n >> 4, m = n & 15;
        int ks = kk >> 5, q = (kk >> 3) & 3, j = kk & 7;
        W1sw[(t16 * 4 + ks) * 512 + (q * 16 + m) * 8 + j] = f2bf(v);
    } else if (t < 65536) {          // W2 [256][128]: n=col (0..127), kk=k (0..255), KS=8
        int u = t - 32768;
        int n = u >> 8, kk = u & 255;
        float v = W2[kk * 128 + n];
        int t16 = n >> 4, m = n & 15;
        int ks = kk >> 5, q = (kk >> 3) & 3, j = kk & 7;
        W2sw[(t16 * 8 + ks) * 512 + (q * 16 + m) * 8 + j] = f2bf(v);
    } else {
        int u = t - 65536;
        if (u < n4) {
            float4 v = nf[u];
            short4 s;
            s.x = f2bf(v.x); s.y = f2bf(v.y); s.z = f2bf(v.z); s.w = f2bf(v.w);
            nfb[u] = s;
        } else {
            int u2 = u - n4;
            if (u2 < N) degi[u2] = 0;
        }
    }
}

// gather over CSR, bf16 input rows [N,128], fp32 accumulate.
// 16 lanes per row, 8 channels (16B) per lane; 8/4/1 edge unroll.
// Edge weight recomputed as dinv[src]*dinv[r] (fp32).
// MODE 0: write bf16 row; MODE 1: write fp32 + bias (final output)
template <int MODE>
__global__ __launch_bounds__(256) void k_gather(const short* __restrict__ xb,
                                                const int* __restrict__ rowstart,
                                                const unsigned short* __restrict__ csr,
                                                const float* __restrict__ dinv,
                                                const float* __restrict__ bias,
                                                float* __restrict__ out,
                                                short* __restrict__ ob, int N) {
    int t = blockIdx.x * 256 + threadIdx.x;
    int r = t >> 4;
    int c = t & 15;              // channels c*8 .. c*8+7
    if (r >= N) return;
    float di = dinv[r];
    float w0 = di * di;
    bf16x8 sv = *(const bf16x8*)(xb + (size_t)r * 128 + c * 8);
    float acc[8];
    #pragma unroll
    for (int j = 0; j < 8; ++j) acc[j] = bf2f(sv[j]) * w0;
    int e0 = rowstart[r], e1 = rowstart[r + 1];
    int e = e0;
    for (; e + 7 < e1; e += 8) {
        int s[8];
        #pragma unroll
        for (int i = 0; i < 8; ++i) s[i] = csr[e + i];
        float w[8];
        #pragma unroll
        for (int i = 0; i < 8; ++i) w[i] = dinv[s[i]] * di;
        bf16x8 x[8];
        #pragma unroll
        for (int i = 0; i < 8; ++i) x[i] = *(const bf16x8*)(xb + (size_t)s[i] * 128 + c * 8);
        #pragma unroll
        for (int i = 0; i < 8; ++i)
            #pragma unroll
            for (int j = 0; j < 8; ++j) acc[j] = fmaf(w[i], bf2f(x[i][j]), acc[j]);
    }
    for (; e + 3 < e1; e += 4) {
        int s[4];
        #pragma unroll
        for (int i = 0; i < 4; ++i) s[i] = csr[e + i];
        float w[4];
        #pragma unroll
        for (int i = 0; i < 4; ++i) w[i] = dinv[s[i]] * di;
        bf16x8 x[4];
        #pragma unroll
        for (int i = 0; i < 4; ++i) x[i] = *(const bf16x8*)(xb + (size_t)s[i] * 128 + c * 8);
        #pragma unroll
        for (int i = 0; i < 4; ++i)
            #pragma unroll
            for (int j = 0; j < 8; ++j) acc[j] = fmaf(w[i], bf2f(x[i][j]), acc[j]);
    }
    for (; e < e1; ++e) {
        int s0 = csr[e];
        float ww = dinv[s0] * di;
        bf16x8 x0 = *(const bf16x8*)(xb + (size_t)s0 * 128 + c * 8);
        #pragma unroll
        for (int j = 0; j < 8; ++j) acc[j] = fmaf(ww, bf2f(x0[j]), acc[j]);
    }
    if (MODE == 0) {
        bf16x8 h;
        #pragma unroll
        for (int j = 0; j < 8; ++j) h[j] = f2bf(acc[j]);
        *(bf16x8*)(ob + (size_t)r * 128 + c * 8) = h;
    } else {
        float4 b0 = *(const float4*)(bias + c * 8);
        float4 b1 = *(const float4*)(bias + c * 8 + 4);
        float4 o0 = make_float4(acc[0] + b0.x, acc[1] + b0.y, acc[2] + b0.z, acc[3] + b0.w);
        float4 o1 = make_float4(acc[4] + b1.x, acc[5] + b1.y, acc[6] + b1.z, acc[7] + b1.w);
        *(float4*)(out + (size_t)r * 128 + c * 8) = o0;
        *(float4*)(out + (size_t)r * 128 + c * 8 + 4) = o1;
    }
}

__device__ __forceinline__ bf16x8 bnrelu8(bf16x8 raw, const float* __restrict__ scsh, int c) {
    float4 sc0 = *(const float4*)(scsh + c);
    float4 sc1 = *(const float4*)(scsh + c + 4);
    float4 sh0 = *(const float4*)(scsh + 256 + c);
    float4 sh1 = *(const float4*)(scsh + 256 + c + 4);
    bf16x8 o;
    o[0] = f2bf(fmaxf(fmaf(bf2f(raw[0]), sc0.x, sh0.x), 0.f));
    o[1] = f2bf(fmaxf(fmaf(bf2f(raw[1]), sc0.y, sh0.y), 0.f));
    o[2] = f2bf(fmaxf(fmaf(bf2f(raw[2]), sc0.z, sh0.z), 0.f));
    o[3] = f2bf(fmaxf(fmaf(bf2f(raw[3]), sc0.w, sh0.w), 0.f));
    o[4] = f2bf(fmaxf(fmaf(bf2f(raw[4]), sc1.x, sh1.x), 0.f));
    o[5] = f2bf(fmaxf(fmaf(bf2f(raw[5]), sc1.y, sh1.y), 0.f));
    o[6] = f2bf(fmaxf(fmaf(bf2f(raw[6]), sc1.z, sh1.z), 0.f));
    o[7] = f2bf(fmaxf(fmaf(bf2f(raw[7]), sc1.w, sh1.w), 0.f));
    return o;
}

// C[M,NOUT](bf16) = f(A)[M,K](bf16) @ W^T (bf16, fragment-swizzled) + bias
// f = identity or BN+ReLU (applied during LDS staging). STATS: per-block partials.
// Block: 256 thr = 4 waves, 64 rows x full NOUT; wave covers NOUT/4 cols (CT tiles).
// A-tile staged in LDS; epilogue staged via LDS for coalesced 16B writes.
template <int K, int NOUT, bool STATS, bool BIAS, bool BNRELU>
__global__ __launch_bounds__(256, 4) void k_gemm(const short* __restrict__ A,
                                                 const short* __restrict__ Bsw,
                                                 const float* __restrict__ bias,
                                                 const float* __restrict__ scsh,
                                                 short* __restrict__ C,
                                                 float* __restrict__ partials, int M) {
    constexpr int CT = NOUT / 64;   // col16-tiles per wave
    constexpr int KS = K / 32;      // k-steps
    constexpr int KP = K + 8;       // padded A row (shorts)
    constexpr int LROW = NOUT + 8;  // padded epilogue row (shorts)
    constexpr int LSZ = (64 * KP > 64 * LROW) ? 64 * KP : 64 * LROW;
    __shared__ __align__(16) short lds[LSZ];
    int tid = threadIdx.x;
    int wave = tid >> 6;
    int lane = tid & 63;
    int m = lane & 15;
    int q = lane >> 4;
    int row0 = blockIdx.x * 64;

    // stage A-tile (64 x K) -> LDS, BN+ReLU fused here when enabled
    constexpr int CPRA = K / 8;     // 16B chunks per A row
    #pragma unroll
    for (int i = 0; i < (64 * CPRA) / 256; ++i) {
        int idx = i * 256 + tid;
        int r = idx / CPRA, cc = idx % CPRA;
        int gr = row0 + r;
        if (gr >= M) gr = M - 1;
        bf16x8 v = *(const bf16x8*)(A + (size_t)gr * K + cc * 8);
        if (BNRELU) v = bnrelu8(v, scsh, cc * 8);
        *(bf16x8*)(lds + r * KP + cc * 8) = v;
    }
    __syncthreads();

    f32x4 acc[4][CT];
    #pragma unroll
    for (int rt = 0; rt < 4; ++rt)
        #pragma unroll
        for (int ct = 0; ct < CT; ++ct)
            acc[rt][ct] = (f32x4){0.f, 0.f, 0.f, 0.f};

    #pragma unroll
    for (int ks = 0; ks < KS; ++ks) {
        bf16x8 bh[CT];
        #pragma unroll
        for (int ct = 0; ct < CT; ++ct)
            bh[ct] = *(const bf16x8*)(Bsw + (size_t)((wave * CT + ct) * KS + ks) * 512 + lane * 8);
        bf16x8 af[4];
        #pragma unroll
        for (int rt = 0; rt < 4; ++rt)
            af[rt] = *(const bf16x8*)(lds + (rt * 16 + m) * KP + ks * 32 + q * 8);
        #pragma unroll
        for (int ct = 0; ct < CT; ++ct)
            #pragma unroll
            for (int rt = 0; rt < 4; ++rt)
                acc[rt][ct] = __builtin_amdgcn_mfma_f32_16x16x32_bf16(af[rt], bh[ct], acc[rt][ct], 0, 0, 0);
    }
    __syncthreads();   // A-tile reads done; reuse LDS for epilogue

    // epilogue: bias (+stats partials), bf16 -> LDS, then coalesced global writes
    #pragma unroll
    for (int ct = 0; ct < CT; ++ct) {
        int col = wave * (NOUT / 4) + ct * 16 + m;
        float bv = BIAS ? bias[col] : 0.f;
        float s = 0.f, sq = 0.f;
        #pragma unroll
        for (int rt = 0; rt < 4; ++rt) {
            #pragma unroll
            for (int r = 0; r < 4; ++r) {
                int lrow = rt * 16 + q * 4 + r;
                float v = acc[rt][ct][r] + bv;
                if (STATS && row0 + lrow < M) { s += v; sq = fmaf(v, v, sq); }
                lds[lrow * LROW + col] = f2bf(v);
            }
        }
        if (STATS) {
            s += __shfl_xor(s, 16, 64);
            s += __shfl_xor(s, 32, 64);
            sq += __shfl_xor(sq, 16, 64);
            sq += __shfl_xor(sq, 32, 64);
            if (lane < 16) {
                partials[(size_t)blockIdx.x * 512 + col] = s;
                partials[(size_t)blockIdx.x * 512 + 256 + col] = sq;
            }
        }
    }
    __syncthreads();
    constexpr int CPR = NOUT / 8;       // 16B chunks per row
    #pragma unroll
    for (int i = 0; i < (64 * CPR) / 256; ++i) {
        int idx = i * 256 + tid;
        int row = idx / CPR;
        int ch = idx % CPR;
        if (row0 + row < M)
            *(bf16x8*)(C + (size_t)(row0 + row) * NOUT + ch * 8) =
                *(const bf16x8*)(lds + row * LROW + ch * 8);
    }
}

// reduce per-block stat partials [nb][512] -> stats[512]; few atomics per addr
__global__ void k_redstats(const float* __restrict__ partials, float* __restrict__ stats,
                           int nb, int rpb) {
    int sid = threadIdx.x;            // 512 threads: stat index
    int r0 = blockIdx.x * rpb;
    int r1 = r0 + rpb;
    if (r1 > nb) r1 = nb;
    float acc = 0.f;
    for (int r = r0; r < r1; ++r) acc += partials[(size_t)r * 512 + sid];
    unsafeAtomicAdd(&stats[sid], acc);
}

__global__ void k_bnfinal(const float* __restrict__ stats, const float* __restrict__ gamma,
                          const float* __restrict__ beta, float* __restrict__ scsh, int N) {
    int c = threadIdx.x;
    float invN = 1.0f / (float)N;
    float mean = stats[c] * invN;
    float var = stats[256 + c] * invN - mean * mean;
    var = fmaxf(var, 0.f);
    float inv = rsqrtf(var + BN_EPS);
    float sc = gamma[c] * inv;
    scsh[c] = sc;
    scsh[256 + c] = fmaf(-mean, sc, beta[c]);
}

extern "C" void kernel_launch(void* const* d_in, const int* in_sizes, int n_in,
                              void* d_out, int out_size, void* d_ws, size_t ws_size,
                              hipStream_t stream) {
    const float* nf    = (const float*)d_in[0];
    const int*   ei    = (const int*)d_in[1];
    const float* W1    = (const float*)d_in[2];
    const float* b1    = (const float*)d_in[3];
    const float* gamma = (const float*)d_in[4];
    const float* beta  = (const float*)d_in[5];
    const float* W2    = (const float*)d_in[6];
    const float* b2    = (const float*)d_in[7];
    float* out = (float*)d_out;

    const int N = in_sizes[0] / CIN;      // 50000
    const int E = in_sizes[1] / 2;        // 800000
    const int* src = ei;
    const int* dst = ei + E;

    const int nb1 = (N + 63) / 64;        // gemm row-blocks (782)

    char* ws = (char*)d_ws;
    auto align256 = [](size_t x) { return (x + 255) & ~(size_t)255; };
    size_t off = 0;
    int*   degi = (int*)(ws + off);      off += align256((size_t)N * 4);
    float* stats = (float*)(ws + off);   off += align256(512 * 4);
    float* dinv = (float*)(ws + off);    off += align256((size_t)N * 4);
    int*   rowstart = (int*)(ws + off);  off += align256((size_t)(N + 1) * 4);
    int*   blocksum = (int*)(ws + off);  off += align256(256 * 4);
    float* scsh = (float*)(ws + off);    off += align256(512 * 4);
    short* W1sw = (short*)(ws + off);    off += align256(32768 * 2);   // swizzled bf16
    short* W2sw = (short*)(ws + off);    off += align256(32768 * 2);
    float* partials = (float*)(ws + off); off += align256((size_t)nb1 * 512 * 4);
    unsigned short* rank = (unsigned short*)(ws + off); off += align256((size_t)E * 2);
    unsigned short* csr = (unsigned short*)(ws + off);  off += align256((size_t)E * 2);
    short* nfb = (short*)(ws + off);     off += align256((size_t)N * CIN * 2);   // nf bf16
    short* agg1b = (short*)(ws + off);   off += align256((size_t)N * CIN * 2);   // S@x bf16
    short* x1b = (short*)(ws + off);     off += align256((size_t)N * CH * 2);    // layer1 bf16
    short* yb = (short*)(ws + off);      off += align256((size_t)N * COUT * 2);  // bnrelu(x1)@W2 bf16

    int nbN = (N + 255) / 256;
    int nbE = (E + 255) / 256;
    int n4 = N * 32;

    // weight prep (swizzle) + feature cast + zero degi/stats (no memset dispatch)
    k_prep<<<(65536 + n4 + N + 255) / 256, 256, 0, stream>>>(
        W1, W2, W1sw, W2sw, (const float4*)nf, (short4*)nfb, degi, stats, n4, N);

    // degree (+ per-edge rank) + norm + CSR build (atomic-free fill)
    k_deg<<<nbE, 256, 0, stream>>>(dst, degi, rank, E);
    k_scan1<<<nbN, 256, 0, stream>>>(degi, dinv, blocksum, N);
    k_scan3<<<nbN, 256, 0, stream>>>(degi, blocksum, nbN, rowstart, N, E);
    k_fill<<<nbE, 256, 0, stream>>>(src, dst, rank, rowstart, csr, E);

    // layer 1 aggregation (gather, bf16 in/out)
    k_gather<0><<<(N * 16 + 255) / 256, 256, 0, stream>>>(
        nfb, rowstart, csr, dinv, nullptr, nullptr, agg1b, N);

    // x1 = agg1 @ W1 + b1, per-block BN-stat partials (no atomics)
    k_gemm<CIN, CH, true, true, false><<<nb1, 256, 0, stream>>>(
        agg1b, W1sw, b1, nullptr, x1b, partials, N);

    // reduce partials -> stats, then BN scale/shift
    {
        int rblocks = 8;
        int rpb = (nb1 + rblocks - 1) / rblocks;
        k_redstats<<<rblocks, 512, 0, stream>>>(partials, stats, nb1, rpb);
    }
    k_bnfinal<<<1, 256, 0, stream>>>(stats, gamma, beta, scsh, N);

    // y = relu(bn(x1)) @ W2  (BN+ReLU fused into A staging; bias deferred to gather)
    k_gemm<CH, COUT, false, false, true><<<nb1, 256, 0, stream>>>(
        x1b, W2sw, nullptr, scsh, yb, nullptr, N);

    // out = S @ y + b2
    k_gather<1><<<(N * 16 + 255) / 256, 256, 0, stream>>>(
        yb, rowstart, csr, dinv, b2, out, nullptr, N);
}